// Round 10
// baseline (702.222 us; speedup 1.0000x reference)
//
#include <hip/hip_runtime.h>

typedef unsigned short u16;
typedef unsigned int u32;
typedef __attribute__((ext_vector_type(8))) short short8;
typedef __attribute__((ext_vector_type(4))) float f32x4;

#define CHSZ 8192     // edges per sort chunk
#define BSH 9         // bucket shift: 512 nodes per bucket
#define FD_CAP 18432  // LDS edge capacity in k_fin_dst (mean 16.3K + 16 sigma)

#define GLOAD_LDS16(g, l) \
    __builtin_amdgcn_global_load_lds((const __attribute__((address_space(1))) void*)(g), \
                                     (__attribute__((address_space(3))) void*)(l), 16, 0, 0)

__device__ __forceinline__ float bf2f(u16 h) {
    return __uint_as_float(((u32)h) << 16);
}
__device__ __forceinline__ u16 f2bf(float f) {
    u32 u = __float_as_uint(f);
    u += 0x7fffu + ((u >> 16) & 1u);   // round-to-nearest-even
    return (u16)(u >> 16);
}
__device__ __forceinline__ float bflo(u32 v) { return __uint_as_float(v << 16); }
__device__ __forceinline__ float bfhi(u32 v) { return __uint_as_float(v & 0xffff0000u); }

// ---------------- sort pass 1a: per-(bucket,chunk) histograms, LDS only ----------------
__global__ __launch_bounds__(256) void k_pcount(const int* __restrict__ src,
                                                const int* __restrict__ dst,
                                                u32* __restrict__ cntD, u32* __restrict__ cntS,
                                                int E, int NC, int nbkt) {
    __shared__ u32 hd[256], hs[256];
    int ch = blockIdx.x, t = threadIdx.x;
    hd[t] = 0; hs[t] = 0;
    __syncthreads();
    int e0 = ch * CHSZ;
    int e1 = e0 + CHSZ; if (e1 > E) e1 = E;
    for (int i = e0 + t * 4; i < e1; i += 1024) {
        if (i + 4 <= e1) {
            int4 s4 = *(const int4*)&src[i];
            int4 d4 = *(const int4*)&dst[i];
            atomicAdd(&hs[(u32)s4.x >> BSH], 1u); atomicAdd(&hd[(u32)d4.x >> BSH], 1u);
            atomicAdd(&hs[(u32)s4.y >> BSH], 1u); atomicAdd(&hd[(u32)d4.y >> BSH], 1u);
            atomicAdd(&hs[(u32)s4.z >> BSH], 1u); atomicAdd(&hd[(u32)d4.z >> BSH], 1u);
            atomicAdd(&hs[(u32)s4.w >> BSH], 1u); atomicAdd(&hd[(u32)d4.w >> BSH], 1u);
        } else {
            for (int k = i; k < e1; ++k) {
                atomicAdd(&hs[(u32)src[k] >> BSH], 1u);
                atomicAdd(&hd[(u32)dst[k] >> BSH], 1u);
            }
        }
    }
    __syncthreads();
    if (t < nbkt) {
        cntD[(size_t)t * NC + ch] = hd[t];
        cntS[(size_t)t * NC + ch] = hs[t];
    }
}

// ---------------- sort pass 1b: in-place exclusive scan of both tables ----------------
__global__ __launch_bounds__(256) void k_pscan(u32* __restrict__ cntD, u32* __restrict__ cntS, int len) {
    __shared__ u32 ls[256];
    u32* a = blockIdx.x ? cntS : cntD;
    int t = threadIdx.x;
    int seg = (len + 255) >> 8;
    int i0 = t * seg, i1 = i0 + seg; if (i1 > len) i1 = len; if (i0 > len) i0 = len;
    u32 s = 0;
    for (int i = i0; i < i1; ++i) s += a[i];
    ls[t] = s; __syncthreads();
    for (int off = 1; off < 256; off <<= 1) {
        u32 v = ls[t] + (t >= off ? ls[t - off] : 0);
        __syncthreads(); ls[t] = v; __syncthreads();
    }
    u32 run = t ? ls[t - 1] : 0;
    for (int i = i0; i < i1; ++i) { u32 v = a[i]; a[i] = run; run += v; }
}

// ---------------- sort pass 2: scatter into bucket partitions (plain stores) ----------------
__global__ __launch_bounds__(256) void k_pscatter(const int* __restrict__ src,
                                                  const int* __restrict__ dst,
                                                  const u32* __restrict__ cntD,
                                                  const u32* __restrict__ cntS,
                                                  u32* __restrict__ partD, u16* __restrict__ partS,
                                                  int E, int NC, int nbkt) {
    __shared__ u32 bd[256], bs[256], rd[256], rs[256];
    int ch = blockIdx.x, t = threadIdx.x;
    if (t < nbkt) {
        bd[t] = cntD[(size_t)t * NC + ch];
        bs[t] = cntS[(size_t)t * NC + ch];
    }
    rd[t] = 0; rs[t] = 0;
    __syncthreads();
    int e0 = ch * CHSZ;
    int e1 = e0 + CHSZ; if (e1 > E) e1 = E;
    for (int i = e0 + t * 4; i < e1; i += 1024) {
        int lim = e1 - i; if (lim > 4) lim = 4;
        int sv[4], dv[4];
        if (lim == 4) {
            int4 s4 = *(const int4*)&src[i];
            int4 d4 = *(const int4*)&dst[i];
            sv[0] = s4.x; sv[1] = s4.y; sv[2] = s4.z; sv[3] = s4.w;
            dv[0] = d4.x; dv[1] = d4.y; dv[2] = d4.z; dv[3] = d4.w;
        } else {
            for (int j = 0; j < lim; ++j) { sv[j] = src[i + j]; dv[j] = dst[i + j]; }
        }
        for (int j = 0; j < lim; ++j) {
            u32 s = (u32)sv[j], d = (u32)dv[j];
            u32 kb = d >> BSH;
            u32 r = atomicAdd(&rd[kb], 1u);
            partD[bd[kb] + r] = (s << BSH) | (d & 511u);
            u32 sb = s >> BSH;
            u32 r2 = atomicAdd(&rs[sb], 1u);
            partS[bs[sb] + r2] = (u16)(s & 511u);
        }
    }
}

// ---------------- finalize dst buckets: rp, inorm, es — all LDS-local ----------------
__global__ __launch_bounds__(256) void k_fin_dst(const u32* __restrict__ partD,
                                                 const u32* __restrict__ cntD,
                                                 int* __restrict__ rp, float* __restrict__ inorm,
                                                 int* __restrict__ es, int E, int NC, int nbkt, int N) {
    __shared__ u32 eb[FD_CAP];
    __shared__ u32 cnt[512], excl[512], cur[512], tmp[512];
    int b = blockIdx.x, t = threadIdx.x;
    int start = (int)cntD[(size_t)b * NC];
    int end = (b + 1 < nbkt) ? (int)cntD[(size_t)(b + 1) * NC] : E;
    int M = end - start;
    for (int i = t; i < 512; i += 256) { cnt[i] = 0; cur[i] = 0; }
    int Ml = M < FD_CAP ? M : FD_CAP;
    for (int i = t; i < Ml; i += 256) eb[i] = partD[start + i];
    __syncthreads();
    // count local dst
    for (int i = t; i < M; i += 256) {
        u32 e = (i < FD_CAP) ? eb[i] : partD[start + i];
        atomicAdd(&cnt[e & 511u], 1u);
    }
    __syncthreads();
    // inclusive scan of 512 in tmp (Hillis-Steele, 256 threads x 2 elements)
    tmp[t] = cnt[t]; tmp[t + 256] = cnt[t + 256];
    __syncthreads();
    for (int off = 1; off < 512; off <<= 1) {
        int i0 = t, i1 = t + 256;
        u32 v0 = tmp[i0] + ((i0 >= off) ? tmp[i0 - off] : 0);
        u32 v1 = tmp[i1] + ((i1 >= off) ? tmp[i1 - off] : 0);
        __syncthreads();
        tmp[i0] = v0; tmp[i1] = v1;
        __syncthreads();
    }
    excl[t] = tmp[t] - cnt[t]; excl[t + 256] = tmp[t + 256] - cnt[t + 256];
    __syncthreads();
    // rp + inorm
    int lo = b << BSH;
    for (int i = t; i < 512; i += 256) {
        int node = lo + i;
        if (node < N) {
            rp[node] = start + (int)excl[i];
            u32 c = cnt[i]; if (c < 1u) c = 1u;
            inorm[node] = 1.0f / sqrtf((float)c);
        }
    }
    if (b == nbkt - 1 && t == 0) rp[N] = E;
    __syncthreads();
    // place: es gets src byte-offsets (64B row stride) grouped by dst
    for (int i = t; i < M; i += 256) {
        u32 e = (i < FD_CAP) ? eb[i] : partD[start + i];
        u32 d9 = e & 511u;
        u32 r = atomicAdd(&cur[d9], 1u);
        es[start + (int)excl[d9] + (int)r] = (int)((e >> BSH) << 6);
    }
}

// ---------------- finalize src buckets: outdeg -> onorm ----------------
__global__ __launch_bounds__(256) void k_fin_src(const u16* __restrict__ partS,
                                                 const u32* __restrict__ cntS,
                                                 float* __restrict__ onorm,
                                                 int E, int NC, int nbkt, int N) {
    __shared__ u32 c[512];
    int b = blockIdx.x, t = threadIdx.x;
    int start = (int)cntS[(size_t)b * NC];
    int end = (b + 1 < nbkt) ? (int)cntS[(size_t)(b + 1) * NC] : E;
    for (int i = t; i < 512; i += 256) c[i] = 0;
    __syncthreads();
    for (int i = start + t; i < end; i += 256) atomicAdd(&c[partS[i] & 511u], 1u);
    __syncthreads();
    int lo = b << BSH;
    for (int i = t; i < 512; i += 256) {
        int node = lo + i;
        if (node < N) {
            u32 v = c[i]; if (v < 1u) v = 1u;
            onorm[node] = 1.0f / sqrtf((float)v);
        }
    }
}

// ---------------- Xb = bf16(onorm * X) ----------------
__global__ __launch_bounds__(256) void k_castx(const float* __restrict__ X,
                                               const float* __restrict__ onorm,
                                               u16* __restrict__ Xb, int total) {
    int stride = gridDim.x * blockDim.x * 4;
    for (int i = (blockIdx.x * blockDim.x + threadIdx.x) * 4; i < total; i += stride) {
        float4 v = *(const float4*)&X[i];
        float s = onorm[i >> 8];
        ushort4 o;
        o.x = f2bf(v.x * s); o.y = f2bf(v.y * s);
        o.z = f2bf(v.z * s); o.w = f2bf(v.w * s);
        *(ushort4*)&Xb[i] = o;
    }
}

// ---------------- Wt[c][k] = bf16(W[k][c]) ----------------
__global__ void k_wt(const float* __restrict__ W, u16* __restrict__ Wt, int K, int C) {
    int i = blockIdx.x * 256 + threadIdx.x;
    if (i < K * C) {
        int k = i / C, c = i - k * C;
        Wt[(size_t)c * K + k] = f2bf(W[i]);
    }
}

// ---------------- bf16 MFMA GEMM ----------------
// C[M][CT] = in[M][256] @ W[256][CT], in/W bf16, fp32 accum.
// in: GWIN ? grouped [256/GWIN][M][GWIN] : row-major [M][256]
// out: GWOUT ? grouped [BN-cols/GWOUT...][M][GWOUT] : row-major [M][BN]
// Block tile 128 x BN, 4 waves (WM x WN).
template <int BN, int WM, int WN, int GWIN, int GWOUT>
__global__ __launch_bounds__(256) void k_gemm(const u16* __restrict__ in,
                                              const u16* __restrict__ Wt,
                                              u16* __restrict__ outp, int M) {
    constexpr int WTM = 128 / WM, WTN = BN / WN;
    constexpr int FM = WTM / 16, FN = WTN / 16;
    constexpr int BROUNDS = (BN * 64) / 4096;

    __shared__ u16 sA[128][32];
    __shared__ u16 sB[BN][32];

    int t = threadIdx.x, wid = t >> 6, l = t & 63;
    int wr = wid / WN, wc = wid % WN;
    int r0 = blockIdx.x * 128;
    int c0 = blockIdx.y * BN;

    f32x4 acc[FM][FN] = {};

    for (int kc = 0; kc < 256; kc += 32) {
        // stage A tile: 8KB = 2 rounds of (256 threads x 16B)
#pragma unroll
        for (int r = 0; r < 2; ++r) {
            int off = r * 4096 + t * 16;
            int row = off >> 6;
            int ko = (off & 63) >> 1;
            int grow = r0 + row; if (grow >= M) grow = M - 1;
            const u16* gp;
            if constexpr (GWIN == 0)
                gp = in + (size_t)grow * 256 + kc + ko;
            else
                gp = in + ((size_t)(kc / GWIN) * M + grow) * GWIN + (kc % GWIN) + ko;
            GLOAD_LDS16(gp, (char*)&sA[0][0] + r * 4096 + wid * 1024);
        }
        // stage B tile (transposed W: [col][k])
#pragma unroll
        for (int r = 0; r < BROUNDS; ++r) {
            int off = r * 4096 + t * 16;
            int col = off >> 6;
            int ko = (off & 63) >> 1;
            const u16* gp = Wt + (size_t)(c0 + col) * 256 + kc + ko;
            GLOAD_LDS16(gp, (char*)&sB[0][0] + r * 4096 + wid * 1024);
        }
        __syncthreads();

        short8 a[FM], b[FN];
#pragma unroll
        for (int m = 0; m < FM; ++m)
            a[m] = *(const short8*)&sA[wr * WTM + m * 16 + (l & 15)][(l >> 4) * 8];
#pragma unroll
        for (int n = 0; n < FN; ++n)
            b[n] = *(const short8*)&sB[wc * WTN + n * 16 + (l & 15)][(l >> 4) * 8];
#pragma unroll
        for (int m = 0; m < FM; ++m)
#pragma unroll
            for (int n = 0; n < FN; ++n)
                acc[m][n] = __builtin_amdgcn_mfma_f32_16x16x32_bf16(a[m], b[n], acc[m][n], 0, 0, 0);
        __syncthreads();
    }

    // epilogue: D layout col = lane&15, row = (lane>>4)*4 + e  [verified m89/m91]
#pragma unroll
    for (int m = 0; m < FM; ++m) {
#pragma unroll
        for (int n = 0; n < FN; ++n) {
#pragma unroll
            for (int e = 0; e < 4; ++e) {
                int row = r0 + wr * WTM + m * 16 + (l >> 4) * 4 + e;
                int col = c0 + wc * WTN + n * 16 + (l & 15);
                if (row < M) {
                    u16 v = f2bf(acc[m][n][e]);
                    if constexpr (GWOUT == 0)
                        outp[(size_t)row * BN + col] = v;
                    else
                        outp[((size_t)(col / GWOUT) * M + row) * GWOUT + (col % GWOUT)] = v;
                }
            }
        }
    }
}

// ---------------- SpMM layer 1: 8x 32-dim groups, XCD-affine, 64B line gathers ----------------
// A8[8][N][32] -> B8[8][N][32]
// lane l: slot j0=l>>3 handles edge i+8j+j0; q=l&7 covers dims q*4..q*4+3 of group g.
__global__ __launch_bounds__(256) void k_spmm1(const u16* __restrict__ A8,
                                               const int* __restrict__ rp,
                                               const int* __restrict__ es,
                                               const float* __restrict__ inorm,
                                               const float* __restrict__ onorm,
                                               const float* __restrict__ b1,
                                               u16* __restrict__ B8, int N) {
    int t = threadIdx.x, w = t >> 6, l = t & 63;
    int j0 = l >> 3, q = l & 7;
    int g = blockIdx.x & 7;               // grid=2048 co-resident -> group g pinned to XCD g
    int bi = blockIdx.x >> 3;
    int nb = gridDim.x >> 3;
    const char* __restrict__ Ag = (const char*)(A8 + (size_t)g * N * 32);
    char* __restrict__ Bg = (char*)(B8 + (size_t)g * N * 32);
    float4 bias = *(const float4*)(b1 + g * 32 + q * 4);
    u32 qo = (u32)q * 8;

    for (int r0 = bi * 4; r0 < N; r0 += nb * 4) {
        int row = r0 + w;
        if (row >= N) continue;
        int beg = rp[row], end = rp[row + 1];
        float a0 = 0.f, a1 = 0.f, a2 = 0.f, a3 = 0.f;
        int i = beg;
        // 32-edge blocks: 4 gathers in flight per lane
        for (; i + 32 <= end; i += 32) {
            u32 s[4]; uint2 v[4];
#pragma unroll
            for (int j = 0; j < 4; ++j) s[j] = (u32)es[i + 8 * j + j0];
#pragma unroll
            for (int j = 0; j < 4; ++j) v[j] = *(const uint2*)(Ag + (s[j] + qo));
#pragma unroll
            for (int j = 0; j < 4; ++j) {
                a0 += bflo(v[j].x); a1 += bfhi(v[j].x);
                a2 += bflo(v[j].y); a3 += bfhi(v[j].y);
            }
        }
        // 8-edge blocks
        for (; i + 8 <= end; i += 8) {
            u32 s = (u32)es[i + j0];
            uint2 v = *(const uint2*)(Ag + (s + qo));
            a0 += bflo(v.x); a1 += bfhi(v.x);
            a2 += bflo(v.y); a3 += bfhi(v.y);
        }
        // tail (<8), predicated
        if (i < end) {
            int e0 = i + j0;
            u32 s = (u32)es[e0 < end ? e0 : beg];
            uint2 v = *(const uint2*)(Ag + (s + qo));
            if (e0 < end) {
                a0 += bflo(v.x); a1 += bfhi(v.x);
                a2 += bflo(v.y); a3 += bfhi(v.y);
            }
        }
        // merge 8 slots
        a0 += __shfl_xor(a0, 8);  a1 += __shfl_xor(a1, 8);
        a2 += __shfl_xor(a2, 8);  a3 += __shfl_xor(a3, 8);
        a0 += __shfl_xor(a0, 16); a1 += __shfl_xor(a1, 16);
        a2 += __shfl_xor(a2, 16); a3 += __shfl_xor(a3, 16);
        a0 += __shfl_xor(a0, 32); a1 += __shfl_xor(a1, 32);
        a2 += __shfl_xor(a2, 32); a3 += __shfl_xor(a3, 32);
        if (j0 == 0) {
            float in_ = inorm[row], on_ = onorm[row];
            float h0 = fmaxf(in_ * a0 + bias.x, 0.f) * on_;
            float h1 = fmaxf(in_ * a1 + bias.y, 0.f) * on_;
            float h2 = fmaxf(in_ * a2 + bias.z, 0.f) * on_;
            float h3 = fmaxf(in_ * a3 + bias.w, 0.f) * on_;
            uint2 pk;
            pk.x = (u32)f2bf(h0) | ((u32)f2bf(h1) << 16);
            pk.y = (u32)f2bf(h2) | ((u32)f2bf(h3) << 16);
            *(uint2*)(Bg + (size_t)row * 64 + qo) = pk;
        }
    }
}

// ---------------- SpMM layer 2: 2x 32-dim groups, same structure, fp32 out ----------------
// Z2[2][N][32]; lane: j0=l>>3 edge slot, q=l&7 dims q*4..q*4+3 of group g2.
__global__ __launch_bounds__(256) void k_spmm_out(const u16* __restrict__ Z2,
                                                  const int* __restrict__ rp,
                                                  const int* __restrict__ es,
                                                  const float* __restrict__ inorm,
                                                  const float* __restrict__ bias,
                                                  float* __restrict__ out, int N) {
    int t = threadIdx.x, w = t >> 6, l = t & 63;
    int j0 = l >> 3, q = l & 7;
    int g = blockIdx.x & 1;
    int bi = blockIdx.x >> 1;
    int nb = gridDim.x >> 1;
    const char* __restrict__ Zg = (const char*)(Z2 + (size_t)g * N * 32);
    float4 bv = *(const float4*)(bias + g * 32 + q * 4);
    u32 qo = (u32)q * 8;

    for (int r0 = bi * 4; r0 < N; r0 += nb * 4) {
        int row = r0 + w;
        if (row >= N) continue;
        int beg = rp[row], end = rp[row + 1];
        float a0 = 0.f, a1 = 0.f, a2 = 0.f, a3 = 0.f;
        int i = beg;
        for (; i + 32 <= end; i += 32) {
            u32 s[4]; uint2 v[4];
#pragma unroll
            for (int j = 0; j < 4; ++j) s[j] = (u32)es[i + 8 * j + j0];
#pragma unroll
            for (int j = 0; j < 4; ++j) v[j] = *(const uint2*)(Zg + (s[j] + qo));
#pragma unroll
            for (int j = 0; j < 4; ++j) {
                a0 += bflo(v[j].x); a1 += bfhi(v[j].x);
                a2 += bflo(v[j].y); a3 += bfhi(v[j].y);
            }
        }
        for (; i + 8 <= end; i += 8) {
            u32 s = (u32)es[i + j0];
            uint2 v = *(const uint2*)(Zg + (s + qo));
            a0 += bflo(v.x); a1 += bfhi(v.x);
            a2 += bflo(v.y); a3 += bfhi(v.y);
        }
        if (i < end) {
            int e0 = i + j0;
            u32 s = (u32)es[e0 < end ? e0 : beg];
            uint2 v = *(const uint2*)(Zg + (s + qo));
            if (e0 < end) {
                a0 += bflo(v.x); a1 += bfhi(v.x);
                a2 += bflo(v.y); a3 += bfhi(v.y);
            }
        }
        a0 += __shfl_xor(a0, 8);  a1 += __shfl_xor(a1, 8);
        a2 += __shfl_xor(a2, 8);  a3 += __shfl_xor(a3, 8);
        a0 += __shfl_xor(a0, 16); a1 += __shfl_xor(a1, 16);
        a2 += __shfl_xor(a2, 16); a3 += __shfl_xor(a3, 16);
        a0 += __shfl_xor(a0, 32); a1 += __shfl_xor(a1, 32);
        a2 += __shfl_xor(a2, 32); a3 += __shfl_xor(a3, 32);
        if (j0 == 0) {
            float in_ = inorm[row];
            float4 o;
            o.x = in_ * a0 + bv.x; o.y = in_ * a1 + bv.y;
            o.z = in_ * a2 + bv.z; o.w = in_ * a3 + bv.w;
            *(float4*)(out + (size_t)row * 64 + g * 32 + q * 4) = o;
        }
    }
}

extern "C" void kernel_launch(void* const* d_in, const int* in_sizes, int n_in,
                              void* d_out, int out_size, void* d_ws, size_t ws_size,
                              hipStream_t stream) {
    const float* feat = (const float*)d_in[0];
    const float* W1   = (const float*)d_in[1];
    const float* b1   = (const float*)d_in[2];
    const float* W2   = (const float*)d_in[3];
    const float* b2   = (const float*)d_in[4];
    const int*   src  = (const int*)d_in[5];
    const int*   dst  = (const int*)d_in[6];

    const int DIN = 256;
    const int N = in_sizes[0] / DIN;   // 100000
    const int E = in_sizes[5];         // 3200000
    float* out = (float*)d_out;

    const int NC = (E + CHSZ - 1) / CHSZ;     // 391
    const int NBKT = (N + 511) >> BSH;        // 196

    char* base = (char*)d_ws;
    size_t o = 0;
    auto take = [&](size_t b) { size_t r = o; o += (b + 255) & ~(size_t)255; return r; };
    u32* cntD = (u32*)(base + take((size_t)NBKT * NC * 4));
    u32* cntS = (u32*)(base + take((size_t)NBKT * NC * 4));
    u32* partD = (u32*)(base + take((size_t)E * 4));
    u16* partS = (u16*)(base + take((size_t)E * 2));
    float* onorm = (float*)(base + take((size_t)N * 4));
    float* inorm = (float*)(base + take((size_t)N * 4));
    int* rp   = (int*)(base + take((size_t)(N + 1) * 4));
    u16* Wt1  = (u16*)(base + take((size_t)256 * 256 * 2));
    u16* Wt2  = (u16*)(base + take((size_t)64 * 256 * 2));
    int* es   = (int*)(base + take((size_t)E * 4));
    u16* S1   = (u16*)(base + take((size_t)N * 256 * 2));  // Xb, later B8
    u16* S2   = (u16*)(base + take((size_t)N * 256 * 2));  // A8
    u16* S3   = (u16*)(base + take((size_t)N * 64 * 2));   // Z2
    (void)ws_size; (void)n_in; (void)out_size;

    u16* Xb = S1;
    u16* A8 = S2;
    u16* B8 = S1;
    u16* Z2 = S3;

    // ---- CSR build: two-level bucket sort, zero global atomics ----
    k_pcount<<<NC, 256, 0, stream>>>(src, dst, cntD, cntS, E, NC, NBKT);
    k_pscan<<<2, 256, 0, stream>>>(cntD, cntS, NBKT * NC);
    k_pscatter<<<NC, 256, 0, stream>>>(src, dst, cntD, cntS, partD, partS, E, NC, NBKT);
    k_fin_src<<<NBKT, 256, 0, stream>>>(partS, cntS, onorm, E, NC, NBKT, N);
    k_fin_dst<<<NBKT, 256, 0, stream>>>(partD, cntD, rp, inorm, es, E, NC, NBKT, N);

    k_castx<<<8192, 256, 0, stream>>>(feat, onorm, Xb, N * 256);
    k_wt<<<(256 * 256 + 255) / 256, 256, 0, stream>>>(W1, Wt1, 256, 256);
    k_wt<<<(256 * 64 + 255) / 256, 256, 0, stream>>>(W2, Wt2, 256, 64);

    int mtiles = (N + 127) / 128;

    // layer 1: A8 = grouped32(Xb @ W1)
    dim3 g1(mtiles, 2);
    k_gemm<128, 2, 2, 0, 32><<<g1, 256, 0, stream>>>(Xb, Wt1, A8, N);
    k_spmm1<<<2048, 256, 0, stream>>>(A8, rp, es, inorm, onorm, b1, B8, N);

    // layer 2: Z2 = grouped32(B8 @ W2)
    dim3 g2(mtiles, 1);
    k_gemm<64, 4, 1, 32, 32><<<g2, 256, 0, stream>>>(B8, Wt2, Z2, N);
    k_spmm_out<<<2048, 256, 0, stream>>>(Z2, rp, es, inorm, b2, out, N);
}

// Round 12
// 464.305 us; speedup vs baseline: 1.5124x; 1.5124x over previous
//
#include <hip/hip_runtime.h>

typedef unsigned short u16;
typedef unsigned char u8;
typedef unsigned int u32;
typedef __attribute__((ext_vector_type(8))) short short8;
typedef __attribute__((ext_vector_type(4))) float f32x4;
typedef __attribute__((ext_vector_type(2))) float f32x2;

#define CHSZ 8192     // edges per sort chunk
#define BSH 9         // bucket shift: 512 nodes per bucket
#define FD_CAP 18432  // LDS edge capacity in k_fin_dst

#define GLOAD_LDS16(g, l) \
    __builtin_amdgcn_global_load_lds((const __attribute__((address_space(1))) void*)(g), \
                                     (__attribute__((address_space(3))) void*)(l), 16, 0, 0)

__device__ __forceinline__ float bf2f(u16 h) {
    return __uint_as_float(((u32)h) << 16);
}
__device__ __forceinline__ u16 f2bf(float f) {
    u32 u = __float_as_uint(f);
    u += 0x7fffu + ((u >> 16) & 1u);   // round-to-nearest-even
    return (u16)(u >> 16);
}
__device__ __forceinline__ float bflo(u32 v) { return __uint_as_float(v << 16); }
__device__ __forceinline__ float bfhi(u32 v) { return __uint_as_float(v & 0xffff0000u); }
__device__ __forceinline__ u8 f2fp8(float f) {
    return (u8)(__builtin_amdgcn_cvt_pk_fp8_f32(f, f, 0, false) & 0xff);
}

// ---------------- sort pass 1a: per-(bucket,chunk) histograms, LDS only ----------------
__global__ __launch_bounds__(256) void k_pcount(const int* __restrict__ src,
                                                const int* __restrict__ dst,
                                                u32* __restrict__ cntD, u32* __restrict__ cntS,
                                                int E, int NC, int nbkt) {
    __shared__ u32 hd[256], hs[256];
    int ch = blockIdx.x, t = threadIdx.x;
    hd[t] = 0; hs[t] = 0;
    __syncthreads();
    int e0 = ch * CHSZ;
    int e1 = e0 + CHSZ; if (e1 > E) e1 = E;
    for (int i = e0 + t * 4; i < e1; i += 1024) {
        if (i + 4 <= e1) {
            int4 s4 = *(const int4*)&src[i];
            int4 d4 = *(const int4*)&dst[i];
            atomicAdd(&hs[(u32)s4.x >> BSH], 1u); atomicAdd(&hd[(u32)d4.x >> BSH], 1u);
            atomicAdd(&hs[(u32)s4.y >> BSH], 1u); atomicAdd(&hd[(u32)d4.y >> BSH], 1u);
            atomicAdd(&hs[(u32)s4.z >> BSH], 1u); atomicAdd(&hd[(u32)d4.z >> BSH], 1u);
            atomicAdd(&hs[(u32)s4.w >> BSH], 1u); atomicAdd(&hd[(u32)d4.w >> BSH], 1u);
        } else {
            for (int k = i; k < e1; ++k) {
                atomicAdd(&hs[(u32)src[k] >> BSH], 1u);
                atomicAdd(&hd[(u32)dst[k] >> BSH], 1u);
            }
        }
    }
    __syncthreads();
    if (t < nbkt) {
        cntD[(size_t)t * NC + ch] = hd[t];
        cntS[(size_t)t * NC + ch] = hs[t];
    }
}

// ---------------- sort pass 1b: in-place exclusive scan of both tables ----------------
__global__ __launch_bounds__(256) void k_pscan(u32* __restrict__ cntD, u32* __restrict__ cntS, int len) {
    __shared__ u32 ls[256];
    u32* a = blockIdx.x ? cntS : cntD;
    int t = threadIdx.x;
    int seg = (len + 255) >> 8;
    int i0 = t * seg, i1 = i0 + seg; if (i1 > len) i1 = len; if (i0 > len) i0 = len;
    u32 s = 0;
    for (int i = i0; i < i1; ++i) s += a[i];
    ls[t] = s; __syncthreads();
    for (int off = 1; off < 256; off <<= 1) {
        u32 v = ls[t] + (t >= off ? ls[t - off] : 0);
        __syncthreads(); ls[t] = v; __syncthreads();
    }
    u32 run = t ? ls[t - 1] : 0;
    for (int i = i0; i < i1; ++i) { u32 v = a[i]; a[i] = run; run += v; }
}

// ---------------- sort pass 2: scatter into bucket partitions (plain stores) ----------------
__global__ __launch_bounds__(256) void k_pscatter(const int* __restrict__ src,
                                                  const int* __restrict__ dst,
                                                  const u32* __restrict__ cntD,
                                                  const u32* __restrict__ cntS,
                                                  u32* __restrict__ partD, u16* __restrict__ partS,
                                                  int E, int NC, int nbkt) {
    __shared__ u32 bd[256], bs[256], rd[256], rs[256];
    int ch = blockIdx.x, t = threadIdx.x;
    if (t < nbkt) {
        bd[t] = cntD[(size_t)t * NC + ch];
        bs[t] = cntS[(size_t)t * NC + ch];
    }
    rd[t] = 0; rs[t] = 0;
    __syncthreads();
    int e0 = ch * CHSZ;
    int e1 = e0 + CHSZ; if (e1 > E) e1 = E;
    for (int i = e0 + t * 4; i < e1; i += 1024) {
        int lim = e1 - i; if (lim > 4) lim = 4;
        int sv[4], dv[4];
        if (lim == 4) {
            int4 s4 = *(const int4*)&src[i];
            int4 d4 = *(const int4*)&dst[i];
            sv[0] = s4.x; sv[1] = s4.y; sv[2] = s4.z; sv[3] = s4.w;
            dv[0] = d4.x; dv[1] = d4.y; dv[2] = d4.z; dv[3] = d4.w;
        } else {
            for (int j = 0; j < lim; ++j) { sv[j] = src[i + j]; dv[j] = dst[i + j]; }
        }
        for (int j = 0; j < lim; ++j) {
            u32 s = (u32)sv[j], d = (u32)dv[j];
            u32 kb = d >> BSH;
            u32 r = atomicAdd(&rd[kb], 1u);
            partD[bd[kb] + r] = (s << BSH) | (d & 511u);
            u32 sb = s >> BSH;
            u32 r2 = atomicAdd(&rs[sb], 1u);
            partS[bs[sb] + r2] = (u16)(s & 511u);
        }
    }
}

// ---------------- finalize dst buckets: rp, inorm, es — all LDS-local ----------------
__global__ __launch_bounds__(256) void k_fin_dst(const u32* __restrict__ partD,
                                                 const u32* __restrict__ cntD,
                                                 int* __restrict__ rp, float* __restrict__ inorm,
                                                 int* __restrict__ es, int E, int NC, int nbkt, int N) {
    __shared__ u32 eb[FD_CAP];
    __shared__ u32 cnt[512], excl[512], cur[512], tmp[512];
    int b = blockIdx.x, t = threadIdx.x;
    int start = (int)cntD[(size_t)b * NC];
    int end = (b + 1 < nbkt) ? (int)cntD[(size_t)(b + 1) * NC] : E;
    int M = end - start;
    for (int i = t; i < 512; i += 256) { cnt[i] = 0; cur[i] = 0; }
    int Ml = M < FD_CAP ? M : FD_CAP;
    for (int i = t; i < Ml; i += 256) eb[i] = partD[start + i];
    __syncthreads();
    // count local dst
    for (int i = t; i < M; i += 256) {
        u32 e = (i < FD_CAP) ? eb[i] : partD[start + i];
        atomicAdd(&cnt[e & 511u], 1u);
    }
    __syncthreads();
    // inclusive scan of 512 (Hillis-Steele, 256 threads x 2 elements)
    tmp[t] = cnt[t]; tmp[t + 256] = cnt[t + 256];
    __syncthreads();
    for (int off = 1; off < 512; off <<= 1) {
        int i0 = t, i1 = t + 256;
        u32 v0 = tmp[i0] + ((i0 >= off) ? tmp[i0 - off] : 0);
        u32 v1 = tmp[i1] + ((i1 >= off) ? tmp[i1 - off] : 0);
        __syncthreads();
        tmp[i0] = v0; tmp[i1] = v1;
        __syncthreads();
    }
    excl[t] = tmp[t] - cnt[t]; excl[t + 256] = tmp[t + 256] - cnt[t + 256];
    __syncthreads();
    // rp + inorm
    int lo = b << BSH;
    for (int i = t; i < 512; i += 256) {
        int node = lo + i;
        if (node < N) {
            rp[node] = start + (int)excl[i];
            u32 c = cnt[i]; if (c < 1u) c = 1u;
            inorm[node] = 1.0f / sqrtf((float)c);
        }
    }
    if (b == nbkt - 1 && t == 0) rp[N] = E;
    __syncthreads();
    // place: es gets src byte-offsets (128B row stride) grouped by dst
    for (int i = t; i < M; i += 256) {
        u32 e = (i < FD_CAP) ? eb[i] : partD[start + i];
        u32 d9 = e & 511u;
        u32 r = atomicAdd(&cur[d9], 1u);
        es[start + (int)excl[d9] + (int)r] = (int)((e >> BSH) << 7);
    }
}

// ---------------- finalize src buckets: outdeg -> onorm ----------------
__global__ __launch_bounds__(256) void k_fin_src(const u16* __restrict__ partS,
                                                 const u32* __restrict__ cntS,
                                                 float* __restrict__ onorm,
                                                 int E, int NC, int nbkt, int N) {
    __shared__ u32 c[512];
    int b = blockIdx.x, t = threadIdx.x;
    int start = (int)cntS[(size_t)b * NC];
    int end = (b + 1 < nbkt) ? (int)cntS[(size_t)(b + 1) * NC] : E;
    for (int i = t; i < 512; i += 256) c[i] = 0;
    __syncthreads();
    for (int i = start + t; i < end; i += 256) atomicAdd(&c[partS[i] & 511u], 1u);
    __syncthreads();
    int lo = b << BSH;
    for (int i = t; i < 512; i += 256) {
        int node = lo + i;
        if (node < N) {
            u32 v = c[i]; if (v < 1u) v = 1u;
            onorm[node] = 1.0f / sqrtf((float)v);
        }
    }
}

// ---------------- Xb = bf16(onorm * X) ----------------
__global__ __launch_bounds__(256) void k_castx(const float* __restrict__ X,
                                               const float* __restrict__ onorm,
                                               u16* __restrict__ Xb, int total) {
    int stride = gridDim.x * blockDim.x * 4;
    for (int i = (blockIdx.x * blockDim.x + threadIdx.x) * 4; i < total; i += stride) {
        float4 v = *(const float4*)&X[i];
        float s = onorm[i >> 8];
        ushort4 o;
        o.x = f2bf(v.x * s); o.y = f2bf(v.y * s);
        o.z = f2bf(v.z * s); o.w = f2bf(v.w * s);
        *(ushort4*)&Xb[i] = o;
    }
}

// ---------------- Wt[c][k] = bf16(W[k][c]) ----------------
__global__ void k_wt(const float* __restrict__ W, u16* __restrict__ Wt, int K, int C) {
    int i = blockIdx.x * 256 + threadIdx.x;
    if (i < K * C) {
        int k = i / C, c = i - k * C;
        Wt[(size_t)c * K + k] = f2bf(W[i]);
    }
}

// ---------------- bf16 MFMA GEMM ----------------
// C[M][CT] = in[M][256] @ W[256][CT], in/W bf16, fp32 accum.
// in: GWIN ? grouped [256/GWIN][M][GWIN] bf16 : row-major [M][256] bf16
// out: OFP8 ? fp8 grouped [..][M][GWOUT] : bf16 (grouped if GWOUT else [M][BN])
template <int BN, int WM, int WN, int GWIN, int GWOUT, bool OFP8>
__global__ __launch_bounds__(256) void k_gemm(const u16* __restrict__ in,
                                              const u16* __restrict__ Wt,
                                              void* __restrict__ outv, int M) {
    constexpr int WTM = 128 / WM, WTN = BN / WN;
    constexpr int FM = WTM / 16, FN = WTN / 16;
    constexpr int BROUNDS = (BN * 64) / 4096;

    __shared__ u16 sA[128][32];
    __shared__ u16 sB[BN][32];

    int t = threadIdx.x, wid = t >> 6, l = t & 63;
    int wr = wid / WN, wc = wid % WN;
    int r0 = blockIdx.x * 128;
    int c0 = blockIdx.y * BN;

    f32x4 acc[FM][FN] = {};

    for (int kc = 0; kc < 256; kc += 32) {
#pragma unroll
        for (int r = 0; r < 2; ++r) {
            int off = r * 4096 + t * 16;
            int row = off >> 6;
            int ko = (off & 63) >> 1;
            int grow = r0 + row; if (grow >= M) grow = M - 1;
            const u16* gp;
            if constexpr (GWIN == 0)
                gp = in + (size_t)grow * 256 + kc + ko;
            else
                gp = in + ((size_t)(kc / GWIN) * M + grow) * GWIN + (kc % GWIN) + ko;
            GLOAD_LDS16(gp, (char*)&sA[0][0] + r * 4096 + wid * 1024);
        }
#pragma unroll
        for (int r = 0; r < BROUNDS; ++r) {
            int off = r * 4096 + t * 16;
            int col = off >> 6;
            int ko = (off & 63) >> 1;
            const u16* gp = Wt + (size_t)(c0 + col) * 256 + kc + ko;
            GLOAD_LDS16(gp, (char*)&sB[0][0] + r * 4096 + wid * 1024);
        }
        __syncthreads();

        short8 a[FM], b[FN];
#pragma unroll
        for (int m = 0; m < FM; ++m)
            a[m] = *(const short8*)&sA[wr * WTM + m * 16 + (l & 15)][(l >> 4) * 8];
#pragma unroll
        for (int n = 0; n < FN; ++n)
            b[n] = *(const short8*)&sB[wc * WTN + n * 16 + (l & 15)][(l >> 4) * 8];
#pragma unroll
        for (int m = 0; m < FM; ++m)
#pragma unroll
            for (int n = 0; n < FN; ++n)
                acc[m][n] = __builtin_amdgcn_mfma_f32_16x16x32_bf16(a[m], b[n], acc[m][n], 0, 0, 0);
        __syncthreads();
    }

    // epilogue: D layout col = lane&15, row = (lane>>4)*4 + e  [verified m89/m91]
#pragma unroll
    for (int m = 0; m < FM; ++m) {
#pragma unroll
        for (int n = 0; n < FN; ++n) {
#pragma unroll
            for (int e = 0; e < 4; ++e) {
                int row = r0 + wr * WTM + m * 16 + (l >> 4) * 4 + e;
                int col = c0 + wc * WTN + n * 16 + (l & 15);
                if (row < M) {
                    if constexpr (OFP8) {
                        u8* outp = (u8*)outv;
                        outp[((size_t)(col / GWOUT) * M + row) * GWOUT + (col % GWOUT)] =
                            f2fp8(acc[m][n][e]);
                    } else {
                        u16* outp = (u16*)outv;
                        u16 v = f2bf(acc[m][n][e]);
                        if constexpr (GWOUT == 0)
                            outp[(size_t)row * BN + col] = v;
                        else
                            outp[((size_t)(col / GWOUT) * M + row) * GWOUT + (col % GWOUT)] = v;
                    }
                }
            }
        }
    }
}

// ---------------- SpMM layer 1: fp8 table [2][N][128], dword gathers, 2 edges/wave ----------------
// lane l: half h=l>>5 handles edge (i+2j+h), q=l&31 covers dims q*4..q*4+3 of group g.
// es = src*128 = byte offset into the 128B-stride fp8 group table.
__global__ __launch_bounds__(256) void k_spmm1(const u8* __restrict__ A8,
                                               const int* __restrict__ rp,
                                               const int* __restrict__ es,
                                               const float* __restrict__ inorm,
                                               const float* __restrict__ onorm,
                                               const float* __restrict__ b1,
                                               u16* __restrict__ B2, int N) {
    int t = threadIdx.x, w = t >> 6, l = t & 63;
    int h = l >> 5, q = l & 31;
    int g = blockIdx.x & 1;
    int bi = blockIdx.x >> 1;
    int nb = gridDim.x >> 1;
    const u8* __restrict__ Ag = A8 + (size_t)g * N * 128;
    char* __restrict__ Bg = (char*)(B2 + (size_t)g * N * 128);
    float4 bias = *(const float4*)(b1 + g * 128 + q * 4);
    u32 qo4 = (u32)q * 4, qo8 = (u32)q * 8;

    for (int r0 = bi * 4; r0 < N; r0 += nb * 4) {
        int row = r0 + w;
        if (row >= N) continue;
        int beg = rp[row], end = rp[row + 1];
        float a0 = 0.f, a1 = 0.f, a2 = 0.f, a3 = 0.f;
        int i = beg;
        for (; i + 16 <= end; i += 16) {
            u32 s[8]; u32 v[8];
#pragma unroll
            for (int j = 0; j < 8; ++j) s[j] = (u32)es[i + 2 * j + h];
#pragma unroll
            for (int j = 0; j < 8; ++j) v[j] = *(const u32*)(Ag + s[j] + qo4);
#pragma unroll
            for (int j = 0; j < 8; ++j) {
                f32x2 lo = __builtin_amdgcn_cvt_pk_f32_fp8(v[j], false);
                f32x2 hi = __builtin_amdgcn_cvt_pk_f32_fp8(v[j], true);
                a0 += lo.x; a1 += lo.y; a2 += hi.x; a3 += hi.y;
            }
        }
        if (i < end) {
            int e0[8]; u32 s[8]; u32 v[8];
#pragma unroll
            for (int j = 0; j < 8; ++j) {
                e0[j] = i + 2 * j + h;
                s[j] = (u32)es[e0[j] < end ? e0[j] : beg];
            }
#pragma unroll
            for (int j = 0; j < 8; ++j) v[j] = *(const u32*)(Ag + s[j] + qo4);
#pragma unroll
            for (int j = 0; j < 8; ++j)
                if (e0[j] < end) {
                    f32x2 lo = __builtin_amdgcn_cvt_pk_f32_fp8(v[j], false);
                    f32x2 hi = __builtin_amdgcn_cvt_pk_f32_fp8(v[j], true);
                    a0 += lo.x; a1 += lo.y; a2 += hi.x; a3 += hi.y;
                }
        }
        a0 += __shfl_xor(a0, 32); a1 += __shfl_xor(a1, 32);
        a2 += __shfl_xor(a2, 32); a3 += __shfl_xor(a3, 32);
        if (h == 0) {
            float in_ = inorm[row], on_ = onorm[row];
            float h0 = fmaxf(in_ * a0 + bias.x, 0.f) * on_;
            float h1 = fmaxf(in_ * a1 + bias.y, 0.f) * on_;
            float h2 = fmaxf(in_ * a2 + bias.z, 0.f) * on_;
            float h3 = fmaxf(in_ * a3 + bias.w, 0.f) * on_;
            uint2 pk;
            pk.x = (u32)f2bf(h0) | ((u32)f2bf(h1) << 16);
            pk.y = (u32)f2bf(h2) | ((u32)f2bf(h3) << 16);
            *(uint2*)(Bg + (size_t)row * 256 + qo8) = pk;
        }
    }
}

// ---------------- SpMM layer 2: bf16 Z [N][64] (128B rows), dwordx2, 4 edges/wave ----------------
__global__ __launch_bounds__(256) void k_spmm_out(const u16* __restrict__ Z,
                                                  const int* __restrict__ rp,
                                                  const int* __restrict__ es,
                                                  const float* __restrict__ inorm,
                                                  const float* __restrict__ bias,
                                                  float* __restrict__ out, int N) {
    int t = threadIdx.x, w = t >> 6, l = t & 63;
    int sub = l >> 4, q = l & 15;
    float4 bv = *(const float4*)(bias + q * 4);
    const char* __restrict__ Zc = (const char*)Z;
    u32 qo = (u32)q * 8;
    for (int r0 = blockIdx.x * 4; r0 < N; r0 += gridDim.x * 4) {
        int row = r0 + w;
        if (row >= N) continue;
        int beg = rp[row], end = rp[row + 1];
        float a0 = 0.f, a1 = 0.f, a2 = 0.f, a3 = 0.f;
        int i = beg;
        for (; i + 16 <= end; i += 16) {
            u32 s[4]; uint2 v[4];
#pragma unroll
            for (int j = 0; j < 4; ++j) s[j] = (u32)es[i + 4 * j + sub];
#pragma unroll
            for (int j = 0; j < 4; ++j) v[j] = *(const uint2*)(Zc + (s[j] + qo));
#pragma unroll
            for (int j = 0; j < 4; ++j) {
                a0 += bflo(v[j].x); a1 += bfhi(v[j].x);
                a2 += bflo(v[j].y); a3 += bfhi(v[j].y);
            }
        }
        if (i < end) {
            int e0[4]; u32 s[4]; uint2 v[4];
#pragma unroll
            for (int j = 0; j < 4; ++j) {
                e0[j] = i + 4 * j + sub;
                s[j] = (u32)es[e0[j] < end ? e0[j] : beg];
            }
#pragma unroll
            for (int j = 0; j < 4; ++j) v[j] = *(const uint2*)(Zc + (s[j] + qo));
#pragma unroll
            for (int j = 0; j < 4; ++j)
                if (e0[j] < end) {
                    a0 += bflo(v[j].x); a1 += bfhi(v[j].x);
                    a2 += bflo(v[j].y); a3 += bfhi(v[j].y);
                }
        }
        a0 += __shfl_xor(a0, 16); a1 += __shfl_xor(a1, 16);
        a2 += __shfl_xor(a2, 16); a3 += __shfl_xor(a3, 16);
        a0 += __shfl_xor(a0, 32); a1 += __shfl_xor(a1, 32);
        a2 += __shfl_xor(a2, 32); a3 += __shfl_xor(a3, 32);
        if (sub == 0) {
            float in_ = inorm[row];
            float4 o;
            o.x = in_ * a0 + bv.x; o.y = in_ * a1 + bv.y;
            o.z = in_ * a2 + bv.z; o.w = in_ * a3 + bv.w;
            *(float4*)(out + (size_t)row * 64 + q * 4) = o;
        }
    }
}

extern "C" void kernel_launch(void* const* d_in, const int* in_sizes, int n_in,
                              void* d_out, int out_size, void* d_ws, size_t ws_size,
                              hipStream_t stream) {
    const float* feat = (const float*)d_in[0];
    const float* W1   = (const float*)d_in[1];
    const float* b1   = (const float*)d_in[2];
    const float* W2   = (const float*)d_in[3];
    const float* b2   = (const float*)d_in[4];
    const int*   src  = (const int*)d_in[5];
    const int*   dst  = (const int*)d_in[6];

    const int DIN = 256;
    const int N = in_sizes[0] / DIN;   // 100000
    const int E = in_sizes[5];         // 3200000
    float* out = (float*)d_out;

    const int NC = (E + CHSZ - 1) / CHSZ;     // 391
    const int NBKT = (N + 511) >> BSH;        // 196

    char* base = (char*)d_ws;
    size_t o = 0;
    auto take = [&](size_t b) { size_t r = o; o += (b + 255) & ~(size_t)255; return r; };
    u32* cntD = (u32*)(base + take((size_t)NBKT * NC * 4));
    u32* cntS = (u32*)(base + take((size_t)NBKT * NC * 4));
    u32* partD = (u32*)(base + take((size_t)E * 4));
    u16* partS = (u16*)(base + take((size_t)E * 2));
    float* onorm = (float*)(base + take((size_t)N * 4));
    float* inorm = (float*)(base + take((size_t)N * 4));
    int* rp   = (int*)(base + take((size_t)(N + 1) * 4));
    u16* Wt1  = (u16*)(base + take((size_t)256 * 256 * 2));
    u16* Wt2  = (u16*)(base + take((size_t)64 * 256 * 2));
    int* es   = (int*)(base + take((size_t)E * 4));
    u16* S1   = (u16*)(base + take((size_t)N * 256 * 2));  // Xb, later B2
    u16* S2   = (u16*)(base + take((size_t)N * 256 * 2));  // A8 (fp8, 25.6MB of 51MB slot)
    u16* S3   = (u16*)(base + take((size_t)N * 64 * 2));   // Z
    (void)ws_size; (void)n_in; (void)out_size;

    u16* Xb = S1;
    u8*  A8 = (u8*)S2;
    u16* B2 = S1;
    u16* Z  = S3;

    // ---- CSR build: two-level bucket sort, zero global atomics ----
    k_pcount<<<NC, 256, 0, stream>>>(src, dst, cntD, cntS, E, NC, NBKT);
    k_pscan<<<2, 256, 0, stream>>>(cntD, cntS, NBKT * NC);
    k_pscatter<<<NC, 256, 0, stream>>>(src, dst, cntD, cntS, partD, partS, E, NC, NBKT);
    k_fin_src<<<NBKT, 256, 0, stream>>>(partS, cntS, onorm, E, NC, NBKT, N);
    k_fin_dst<<<NBKT, 256, 0, stream>>>(partD, cntD, rp, inorm, es, E, NC, NBKT, N);

    k_castx<<<8192, 256, 0, stream>>>(feat, onorm, Xb, N * 256);
    k_wt<<<(256 * 256 + 255) / 256, 256, 0, stream>>>(W1, Wt1, 256, 256);
    k_wt<<<(256 * 64 + 255) / 256, 256, 0, stream>>>(W2, Wt2, 256, 64);

    int mtiles = (N + 127) / 128;

    // layer 1: A8 = fp8 grouped(Xb @ W1), then spmm -> B2 bf16 grouped
    dim3 g1(mtiles, 2);
    k_gemm<128, 2, 2, 0, 128, true><<<g1, 256, 0, stream>>>(Xb, Wt1, A8, N);
    k_spmm1<<<8192, 256, 0, stream>>>(A8, rp, es, inorm, onorm, b1, B2, N);

    // layer 2: Z = B2 @ W2 (plain [N][64] bf16), then spmm -> out fp32
    dim3 g2(mtiles, 1);
    k_gemm<64, 4, 1, 128, 0, false><<<g2, 256, 0, stream>>>(B2, Wt2, Z, N);
    k_spmm_out<<<8192, 256, 0, stream>>>(Z, rp, es, inorm, b2, out, N);
}

// Round 15
// 341.349 us; speedup vs baseline: 2.0572x; 1.3602x over previous
//
#include <hip/hip_runtime.h>

typedef unsigned short u16;
typedef unsigned char u8;
typedef unsigned int u32;
typedef __attribute__((ext_vector_type(8))) short short8;
typedef __attribute__((ext_vector_type(4))) float f32x4;
typedef __attribute__((ext_vector_type(2))) float f32x2;

#define CHSZ 8192     // edges per sort chunk
#define BSH 9         // bucket shift: 512 nodes per bucket
#define FD_CAP 18432  // LDS edge capacity in k_fin_dst
#define SCB 128       // scan blocks per array

#define GLOAD_LDS16(g, l) \
    __builtin_amdgcn_global_load_lds((const __attribute__((address_space(1))) void*)(g), \
                                     (__attribute__((address_space(3))) void*)(l), 16, 0, 0)

__device__ __forceinline__ float bf2f(u16 h) {
    return __uint_as_float(((u32)h) << 16);
}
__device__ __forceinline__ u16 f2bf(float f) {
    u32 u = __float_as_uint(f);
    u += 0x7fffu + ((u >> 16) & 1u);   // round-to-nearest-even
    return (u16)(u >> 16);
}
__device__ __forceinline__ float bflo(u32 v) { return __uint_as_float(v << 16); }
__device__ __forceinline__ float bfhi(u32 v) { return __uint_as_float(v & 0xffff0000u); }
__device__ __forceinline__ u8 f2fp8(float f) {
    return (u8)(__builtin_amdgcn_cvt_pk_fp8_f32(f, f, 0, false) & 0xff);
}

// ---------------- sort pass 1a: per-(bucket,chunk) histograms, LDS only ----------------
__global__ __launch_bounds__(256) void k_pcount(const int* __restrict__ src,
                                                const int* __restrict__ dst,
                                                u32* __restrict__ cntD, u32* __restrict__ cntS,
                                                int E, int NC, int nbkt) {
    __shared__ u32 hd[256], hs[256];
    int ch = blockIdx.x, t = threadIdx.x;
    hd[t] = 0; hs[t] = 0;
    __syncthreads();
    int e0 = ch * CHSZ;
    int e1 = e0 + CHSZ; if (e1 > E) e1 = E;
    for (int i = e0 + t * 4; i < e1; i += 1024) {
        if (i + 4 <= e1) {
            int4 s4 = *(const int4*)&src[i];
            int4 d4 = *(const int4*)&dst[i];
            atomicAdd(&hs[(u32)s4.x >> BSH], 1u); atomicAdd(&hd[(u32)d4.x >> BSH], 1u);
            atomicAdd(&hs[(u32)s4.y >> BSH], 1u); atomicAdd(&hd[(u32)d4.y >> BSH], 1u);
            atomicAdd(&hs[(u32)s4.z >> BSH], 1u); atomicAdd(&hd[(u32)d4.z >> BSH], 1u);
            atomicAdd(&hs[(u32)s4.w >> BSH], 1u); atomicAdd(&hd[(u32)d4.w >> BSH], 1u);
        } else {
            for (int k = i; k < e1; ++k) {
                atomicAdd(&hs[(u32)src[k] >> BSH], 1u);
                atomicAdd(&hd[(u32)dst[k] >> BSH], 1u);
            }
        }
    }
    __syncthreads();
    if (t < nbkt) {
        cntD[(size_t)t * NC + ch] = hd[t];
        cntS[(size_t)t * NC + ch] = hs[t];
    }
}

// ---------------- parallel 3-pass exclusive scan of both count tables ----------------
__global__ __launch_bounds__(256) void k_scan1(const u32* __restrict__ cntD,
                                               const u32* __restrict__ cntS,
                                               u32* __restrict__ bsum, int len) {
    __shared__ u32 sh[256];
    const u32* __restrict__ a = blockIdx.y ? cntS : cntD;
    int seg = (len + SCB - 1) / SCB;
    int i0 = blockIdx.x * seg;
    int i1 = i0 + seg; if (i1 > len) i1 = len;
    u32 s = 0;
    for (int i = i0 + threadIdx.x; i < i1; i += 256) s += a[i];
    sh[threadIdx.x] = s; __syncthreads();
    for (int off = 128; off > 0; off >>= 1) {
        if (threadIdx.x < off) sh[threadIdx.x] += sh[threadIdx.x + off];
        __syncthreads();
    }
    if (threadIdx.x == 0) bsum[blockIdx.y * SCB + blockIdx.x] = sh[0];
}

// segmented Hillis-Steele over 2 halves of 128 -> exclusive block bases in place
__global__ __launch_bounds__(256) void k_scan2(u32* __restrict__ bsum) {
    __shared__ u32 sh[256];
    int t = threadIdx.x;
    int lane = t & (SCB - 1);
    u32 v = bsum[t];
    sh[t] = v; __syncthreads();
    for (int off = 1; off < SCB; off <<= 1) {
        u32 x = (lane >= off) ? sh[t - off] : 0;
        __syncthreads();
        sh[t] += x;
        __syncthreads();
    }
    bsum[t] = sh[t] - v;   // exclusive within each half
}

__global__ __launch_bounds__(256) void k_scan3(u32* __restrict__ cntD,
                                               u32* __restrict__ cntS,
                                               const u32* __restrict__ bsum, int len) {
    __shared__ u32 sh[256];
    u32* __restrict__ a = blockIdx.y ? cntS : cntD;
    int seg = (len + SCB - 1) / SCB;
    int i0 = blockIdx.x * seg;
    int i1 = i0 + seg; if (i1 > len) i1 = len;
    int per = (seg + 255) >> 8;
    int j0 = i0 + threadIdx.x * per;
    int j1 = j0 + per; if (j1 > i1) j1 = i1; if (j0 > i1) j0 = i1;
    u32 s = 0;
    for (int i = j0; i < j1; ++i) s += a[i];
    sh[threadIdx.x] = s; __syncthreads();
    for (int off = 1; off < 256; off <<= 1) {
        u32 x = (threadIdx.x >= off) ? sh[threadIdx.x - off] : 0;
        __syncthreads();
        sh[threadIdx.x] += x;
        __syncthreads();
    }
    u32 run = bsum[blockIdx.y * SCB + blockIdx.x] + (threadIdx.x ? sh[threadIdx.x - 1] : 0);
    for (int i = j0; i < j1; ++i) { u32 v = a[i]; a[i] = run; run += v; }
}

// ---------------- sort pass 2: scatter into bucket partitions (plain stores) ----------------
__global__ __launch_bounds__(256) void k_pscatter(const int* __restrict__ src,
                                                  const int* __restrict__ dst,
                                                  const u32* __restrict__ cntD,
                                                  const u32* __restrict__ cntS,
                                                  u32* __restrict__ partD, u16* __restrict__ partS,
                                                  int E, int NC, int nbkt) {
    __shared__ u32 bd[256], bs[256], rd[256], rs[256];
    int ch = blockIdx.x, t = threadIdx.x;
    if (t < nbkt) {
        bd[t] = cntD[(size_t)t * NC + ch];
        bs[t] = cntS[(size_t)t * NC + ch];
    }
    rd[t] = 0; rs[t] = 0;
    __syncthreads();
    int e0 = ch * CHSZ;
    int e1 = e0 + CHSZ; if (e1 > E) e1 = E;
    for (int i = e0 + t * 4; i < e1; i += 1024) {
        int lim = e1 - i; if (lim > 4) lim = 4;
        int sv[4], dv[4];
        if (lim == 4) {
            int4 s4 = *(const int4*)&src[i];
            int4 d4 = *(const int4*)&dst[i];
            sv[0] = s4.x; sv[1] = s4.y; sv[2] = s4.z; sv[3] = s4.w;
            dv[0] = d4.x; dv[1] = d4.y; dv[2] = d4.z; dv[3] = d4.w;
        } else {
            for (int j = 0; j < lim; ++j) { sv[j] = src[i + j]; dv[j] = dst[i + j]; }
        }
        for (int j = 0; j < lim; ++j) {
            u32 s = (u32)sv[j], d = (u32)dv[j];
            u32 kb = d >> BSH;
            u32 r = atomicAdd(&rd[kb], 1u);
            partD[bd[kb] + r] = (s << BSH) | (d & 511u);
            u32 sb = s >> BSH;
            u32 r2 = atomicAdd(&rs[sb], 1u);
            partS[bs[sb] + r2] = (u16)(s & 511u);
        }
    }
}

// ---------------- finalize dst buckets: rp, inorm, es — all LDS-local ----------------
__global__ __launch_bounds__(256) void k_fin_dst(const u32* __restrict__ partD,
                                                 const u32* __restrict__ cntD,
                                                 int* __restrict__ rp, float* __restrict__ inorm,
                                                 int* __restrict__ es, int E, int NC, int nbkt, int N) {
    __shared__ u32 eb[FD_CAP];
    __shared__ u32 cnt[512], excl[512], cur[512], tmp[512];
    int b = blockIdx.x, t = threadIdx.x;
    int start = (int)cntD[(size_t)b * NC];
    int end = (b + 1 < nbkt) ? (int)cntD[(size_t)(b + 1) * NC] : E;
    int M = end - start;
    for (int i = t; i < 512; i += 256) { cnt[i] = 0; cur[i] = 0; }
    int Ml = M < FD_CAP ? M : FD_CAP;
    for (int i = t; i < Ml; i += 256) eb[i] = partD[start + i];
    __syncthreads();
    // count local dst
    for (int i = t; i < M; i += 256) {
        u32 e = (i < FD_CAP) ? eb[i] : partD[start + i];
        atomicAdd(&cnt[e & 511u], 1u);
    }
    __syncthreads();
    // inclusive scan of 512 (Hillis-Steele, 256 threads x 2 elements)
    tmp[t] = cnt[t]; tmp[t + 256] = cnt[t + 256];
    __syncthreads();
    for (int off = 1; off < 512; off <<= 1) {
        int i0 = t, i1 = t + 256;
        u32 v0 = tmp[i0] + ((i0 >= off) ? tmp[i0 - off] : 0);
        u32 v1 = tmp[i1] + ((i1 >= off) ? tmp[i1 - off] : 0);
        __syncthreads();
        tmp[i0] = v0; tmp[i1] = v1;
        __syncthreads();
    }
    excl[t] = tmp[t] - cnt[t]; excl[t + 256] = tmp[t + 256] - cnt[t + 256];
    __syncthreads();
    // rp + inorm
    int lo = b << BSH;
    for (int i = t; i < 512; i += 256) {
        int node = lo + i;
        if (node < N) {
            rp[node] = start + (int)excl[i];
            u32 c = cnt[i]; if (c < 1u) c = 1u;
            inorm[node] = 1.0f / sqrtf((float)c);
        }
    }
    if (b == nbkt - 1 && t == 0) rp[N] = E;
    __syncthreads();
    // place: es gets src byte-offsets (128B row stride) grouped by dst
    for (int i = t; i < M; i += 256) {
        u32 e = (i < FD_CAP) ? eb[i] : partD[start + i];
        u32 d9 = e & 511u;
        u32 r = atomicAdd(&cur[d9], 1u);
        es[start + (int)excl[d9] + (int)r] = (int)((e >> BSH) << 7);
    }
}

// ---------------- finalize src buckets: outdeg -> onorm ----------------
__global__ __launch_bounds__(256) void k_fin_src(const u16* __restrict__ partS,
                                                 const u32* __restrict__ cntS,
                                                 float* __restrict__ onorm,
                                                 int E, int NC, int nbkt, int N) {
    __shared__ u32 c[512];
    int b = blockIdx.x, t = threadIdx.x;
    int start = (int)cntS[(size_t)b * NC];
    int end = (b + 1 < nbkt) ? (int)cntS[(size_t)(b + 1) * NC] : E;
    for (int i = t; i < 512; i += 256) c[i] = 0;
    __syncthreads();
    for (int i = start + t; i < end; i += 256) atomicAdd(&c[partS[i] & 511u], 1u);
    __syncthreads();
    int lo = b << BSH;
    for (int i = t; i < 512; i += 256) {
        int node = lo + i;
        if (node < N) {
            u32 v = c[i]; if (v < 1u) v = 1u;
            onorm[node] = 1.0f / sqrtf((float)v);
        }
    }
}

// ---------------- Xb = bf16(onorm * X) ----------------
__global__ __launch_bounds__(256) void k_castx(const float* __restrict__ X,
                                               const float* __restrict__ onorm,
                                               u16* __restrict__ Xb, int total) {
    int stride = gridDim.x * blockDim.x * 4;
    for (int i = (blockIdx.x * blockDim.x + threadIdx.x) * 4; i < total; i += stride) {
        float4 v = *(const float4*)&X[i];
        float s = onorm[i >> 8];
        ushort4 o;
        o.x = f2bf(v.x * s); o.y = f2bf(v.y * s);
        o.z = f2bf(v.z * s); o.w = f2bf(v.w * s);
        *(ushort4*)&Xb[i] = o;
    }
}

// ---------------- Wt[c][k] = bf16(W[k][c]) ----------------
__global__ void k_wt(const float* __restrict__ W, u16* __restrict__ Wt, int K, int C) {
    int i = blockIdx.x * 256 + threadIdx.x;
    if (i < K * C) {
        int k = i / C, c = i - k * C;
        Wt[(size_t)c * K + k] = f2bf(W[i]);
    }
}

// ---------------- bf16 MFMA GEMM ----------------
template <int BN, int WM, int WN, int GWIN, int GWOUT, bool OFP8>
__global__ __launch_bounds__(256) void k_gemm(const u16* __restrict__ in,
                                              const u16* __restrict__ Wt,
                                              void* __restrict__ outv, int M) {
    constexpr int WTM = 128 / WM, WTN = BN / WN;
    constexpr int FM = WTM / 16, FN = WTN / 16;
    constexpr int BROUNDS = (BN * 64) / 4096;

    __shared__ u16 sA[128][32];
    __shared__ u16 sB[BN][32];

    int t = threadIdx.x, wid = t >> 6, l = t & 63;
    int wr = wid / WN, wc = wid % WN;
    int r0 = blockIdx.x * 128;
    int c0 = blockIdx.y * BN;

    f32x4 acc[FM][FN] = {};

    for (int kc = 0; kc < 256; kc += 32) {
#pragma unroll
        for (int r = 0; r < 2; ++r) {
            int off = r * 4096 + t * 16;
            int row = off >> 6;
            int ko = (off & 63) >> 1;
            int grow = r0 + row; if (grow >= M) grow = M - 1;
            const u16* gp;
            if constexpr (GWIN == 0)
                gp = in + (size_t)grow * 256 + kc + ko;
            else
                gp = in + ((size_t)(kc / GWIN) * M + grow) * GWIN + (kc % GWIN) + ko;
            GLOAD_LDS16(gp, (char*)&sA[0][0] + r * 4096 + wid * 1024);
        }
#pragma unroll
        for (int r = 0; r < BROUNDS; ++r) {
            int off = r * 4096 + t * 16;
            int col = off >> 6;
            int ko = (off & 63) >> 1;
            const u16* gp = Wt + (size_t)(c0 + col) * 256 + kc + ko;
            GLOAD_LDS16(gp, (char*)&sB[0][0] + r * 4096 + wid * 1024);
        }
        __syncthreads();

        short8 a[FM], b[FN];
#pragma unroll
        for (int m = 0; m < FM; ++m)
            a[m] = *(const short8*)&sA[wr * WTM + m * 16 + (l & 15)][(l >> 4) * 8];
#pragma unroll
        for (int n = 0; n < FN; ++n)
            b[n] = *(const short8*)&sB[wc * WTN + n * 16 + (l & 15)][(l >> 4) * 8];
#pragma unroll
        for (int m = 0; m < FM; ++m)
#pragma unroll
            for (int n = 0; n < FN; ++n)
                acc[m][n] = __builtin_amdgcn_mfma_f32_16x16x32_bf16(a[m], b[n], acc[m][n], 0, 0, 0);
        __syncthreads();
    }

    // epilogue: D layout col = lane&15, row = (lane>>4)*4 + e  [verified m89/m91]
#pragma unroll
    for (int m = 0; m < FM; ++m) {
#pragma unroll
        for (int n = 0; n < FN; ++n) {
#pragma unroll
            for (int e = 0; e < 4; ++e) {
                int row = r0 + wr * WTM + m * 16 + (l >> 4) * 4 + e;
                int col = c0 + wc * WTN + n * 16 + (l & 15);
                if (row < M) {
                    if constexpr (OFP8) {
                        u8* outp = (u8*)outv;
                        outp[((size_t)(col / GWOUT) * M + row) * GWOUT + (col % GWOUT)] =
                            f2fp8(acc[m][n][e]);
                    } else {
                        u16* outp = (u16*)outv;
                        u16 v = f2bf(acc[m][n][e]);
                        if constexpr (GWOUT == 0)
                            outp[(size_t)row * BN + col] = v;
                        else
                            outp[((size_t)(col / GWOUT) * M + row) * GWOUT + (col % GWOUT)] = v;
                    }
                }
            }
        }
    }
}

// ---------------- SpMM layer 1: fp8 table [2][N][128], dword gathers, 2 edges/wave ----------------
__global__ __launch_bounds__(256) void k_spmm1(const u8* __restrict__ A8,
                                               const int* __restrict__ rp,
                                               const int* __restrict__ es,
                                               const float* __restrict__ inorm,
                                               const float* __restrict__ onorm,
                                               const float* __restrict__ b1,
                                               u16* __restrict__ B2, int N) {
    int t = threadIdx.x, w = t >> 6, l = t & 63;
    int h = l >> 5, q = l & 31;
    int g = blockIdx.x & 1;
    int bi = blockIdx.x >> 1;
    int nb = gridDim.x >> 1;
    const u8* __restrict__ Ag = A8 + (size_t)g * N * 128;
    char* __restrict__ Bg = (char*)(B2 + (size_t)g * N * 128);
    float4 bias = *(const float4*)(b1 + g * 128 + q * 4);
    u32 qo4 = (u32)q * 4, qo8 = (u32)q * 8;

    for (int r0 = bi * 4; r0 < N; r0 += nb * 4) {
        int row = r0 + w;
        if (row >= N) continue;
        int beg = rp[row], end = rp[row + 1];
        float a0 = 0.f, a1 = 0.f, a2 = 0.f, a3 = 0.f;
        int i = beg;
        for (; i + 16 <= end; i += 16) {
            u32 s[8]; u32 v[8];
#pragma unroll
            for (int j = 0; j < 8; ++j) s[j] = (u32)es[i + 2 * j + h];
#pragma unroll
            for (int j = 0; j < 8; ++j) v[j] = *(const u32*)(Ag + s[j] + qo4);
#pragma unroll
            for (int j = 0; j < 8; ++j) {
                f32x2 lo = __builtin_amdgcn_cvt_pk_f32_fp8(v[j], false);
                f32x2 hi = __builtin_amdgcn_cvt_pk_f32_fp8(v[j], true);
                a0 += lo.x; a1 += lo.y; a2 += hi.x; a3 += hi.y;
            }
        }
        if (i < end) {
            int e0[8]; u32 s[8]; u32 v[8];
#pragma unroll
            for (int j = 0; j < 8; ++j) {
                e0[j] = i + 2 * j + h;
                s[j] = (u32)es[e0[j] < end ? e0[j] : beg];
            }
#pragma unroll
            for (int j = 0; j < 8; ++j) v[j] = *(const u32*)(Ag + s[j] + qo4);
#pragma unroll
            for (int j = 0; j < 8; ++j)
                if (e0[j] < end) {
                    f32x2 lo = __builtin_amdgcn_cvt_pk_f32_fp8(v[j], false);
                    f32x2 hi = __builtin_amdgcn_cvt_pk_f32_fp8(v[j], true);
                    a0 += lo.x; a1 += lo.y; a2 += hi.x; a3 += hi.y;
                }
        }
        a0 += __shfl_xor(a0, 32); a1 += __shfl_xor(a1, 32);
        a2 += __shfl_xor(a2, 32); a3 += __shfl_xor(a3, 32);
        if (h == 0) {
            float in_ = inorm[row], on_ = onorm[row];
            float h0 = fmaxf(in_ * a0 + bias.x, 0.f) * on_;
            float h1 = fmaxf(in_ * a1 + bias.y, 0.f) * on_;
            float h2 = fmaxf(in_ * a2 + bias.z, 0.f) * on_;
            float h3 = fmaxf(in_ * a3 + bias.w, 0.f) * on_;
            uint2 pk;
            pk.x = (u32)f2bf(h0) | ((u32)f2bf(h1) << 16);
            pk.y = (u32)f2bf(h2) | ((u32)f2bf(h3) << 16);
            *(uint2*)(Bg + (size_t)row * 256 + qo8) = pk;
        }
    }
}

// ---------------- SpMM layer 2: bf16 Z [N][64] (128B rows), dwordx2, 4 edges/wave ----------------
__global__ __launch_bounds__(256) void k_spmm_out(const u16* __restrict__ Z,
                                                  const int* __restrict__ rp,
                                                  const int* __restrict__ es,
                                                  const float* __restrict__ inorm,
                                                  const float* __restrict__ bias,
                                                  float* __restrict__ out, int N) {
    int t = threadIdx.x, w = t >> 6, l = t & 63;
    int sub = l >> 4, q = l & 15;
    float4 bv = *(const float4*)(bias + q * 4);
    const char* __restrict__ Zc = (const char*)Z;
    u32 qo = (u32)q * 8;
    for (int r0 = blockIdx.x * 4; r0 < N; r0 += gridDim.x * 4) {
        int row = r0 + w;
        if (row >= N) continue;
        int beg = rp[row], end = rp[row + 1];
        float a0 = 0.f, a1 = 0.f, a2 = 0.f, a3 = 0.f;
        int i = beg;
        for (; i + 16 <= end; i += 16) {
            u32 s[4]; uint2 v[4];
#pragma unroll
            for (int j = 0; j < 4; ++j) s[j] = (u32)es[i + 4 * j + sub];
#pragma unroll
            for (int j = 0; j < 4; ++j) v[j] = *(const uint2*)(Zc + (s[j] + qo));
#pragma unroll
            for (int j = 0; j < 4; ++j) {
                a0 += bflo(v[j].x); a1 += bfhi(v[j].x);
                a2 += bflo(v[j].y); a3 += bfhi(v[j].y);
            }
        }
        if (i < end) {
            int e0[4]; u32 s[4]; uint2 v[4];
#pragma unroll
            for (int j = 0; j < 4; ++j) {
                e0[j] = i + 4 * j + sub;
                s[j] = (u32)es[e0[j] < end ? e0[j] : beg];
            }
#pragma unroll
            for (int j = 0; j < 4; ++j) v[j] = *(const uint2*)(Zc + (s[j] + qo));
#pragma unroll
            for (int j = 0; j < 4; ++j)
                if (e0[j] < end) {
                    a0 += bflo(v[j].x); a1 += bfhi(v[j].x);
                    a2 += bflo(v[j].y); a3 += bfhi(v[j].y);
                }
        }
        a0 += __shfl_xor(a0, 16); a1 += __shfl_xor(a1, 16);
        a2 += __shfl_xor(a2, 16); a3 += __shfl_xor(a3, 16);
        a0 += __shfl_xor(a0, 32); a1 += __shfl_xor(a1, 32);
        a2 += __shfl_xor(a2, 32); a3 += __shfl_xor(a3, 32);
        if (sub == 0) {
            float in_ = inorm[row];
            float4 o;
            o.x = in_ * a0 + bv.x; o.y = in_ * a1 + bv.y;
            o.z = in_ * a2 + bv.z; o.w = in_ * a3 + bv.w;
            *(float4*)(out + (size_t)row * 64 + q * 4) = o;
        }
    }
}

extern "C" void kernel_launch(void* const* d_in, const int* in_sizes, int n_in,
                              void* d_out, int out_size, void* d_ws, size_t ws_size,
                              hipStream_t stream) {
    const float* feat = (const float*)d_in[0];
    const float* W1   = (const float*)d_in[1];
    const float* b1   = (const float*)d_in[2];
    const float* W2   = (const float*)d_in[3];
    const float* b2   = (const float*)d_in[4];
    const int*   src  = (const int*)d_in[5];
    const int*   dst  = (const int*)d_in[6];

    const int DIN = 256;
    const int N = in_sizes[0] / DIN;   // 100000
    const int E = in_sizes[5];         // 3200000
    float* out = (float*)d_out;

    const int NC = (E + CHSZ - 1) / CHSZ;     // 391
    const int NBKT = (N + 511) >> BSH;        // 196

    char* base = (char*)d_ws;
    size_t o = 0;
    auto take = [&](size_t b) { size_t r = o; o += (b + 255) & ~(size_t)255; return r; };
    u32* cntD = (u32*)(base + take((size_t)NBKT * NC * 4));
    u32* cntS = (u32*)(base + take((size_t)NBKT * NC * 4));
    u32* bsum = (u32*)(base + take((size_t)2 * SCB * 4));
    u32* partD = (u32*)(base + take((size_t)E * 4));
    u16* partS = (u16*)(base + take((size_t)E * 2));
    float* onorm = (float*)(base + take((size_t)N * 4));
    float* inorm = (float*)(base + take((size_t)N * 4));
    int* rp   = (int*)(base + take((size_t)(N + 1) * 4));
    u16* Wt1  = (u16*)(base + take((size_t)256 * 256 * 2));
    u16* Wt2  = (u16*)(base + take((size_t)64 * 256 * 2));
    int* es   = (int*)(base + take((size_t)E * 4));
    u16* S1   = (u16*)(base + take((size_t)N * 256 * 2));  // Xb, later B2
    u16* S2   = (u16*)(base + take((size_t)N * 256 * 2));  // A8 (fp8)
    u16* S3   = (u16*)(base + take((size_t)N * 64 * 2));   // Z
    (void)ws_size; (void)n_in; (void)out_size;

    u16* Xb = S1;
    u8*  A8 = (u8*)S2;
    u16* B2 = S1;
    u16* Z  = S3;

    // ---- CSR build: two-level bucket sort, zero global atomics ----
    int len = NBKT * NC;
    k_pcount<<<NC, 256, 0, stream>>>(src, dst, cntD, cntS, E, NC, NBKT);
    dim3 gs(SCB, 2);
    k_scan1<<<gs, 256, 0, stream>>>(cntD, cntS, bsum, len);
    k_scan2<<<1, 256, 0, stream>>>(bsum);
    k_scan3<<<gs, 256, 0, stream>>>(cntD, cntS, bsum, len);
    k_pscatter<<<NC, 256, 0, stream>>>(src, dst, cntD, cntS, partD, partS, E, NC, NBKT);
    k_fin_src<<<NBKT, 256, 0, stream>>>(partS, cntS, onorm, E, NC, NBKT, N);
    k_fin_dst<<<NBKT, 256, 0, stream>>>(partD, cntD, rp, inorm, es, E, NC, NBKT, N);

    k_castx<<<8192, 256, 0, stream>>>(feat, onorm, Xb, N * 256);
    k_wt<<<(256 * 256 + 255) / 256, 256, 0, stream>>>(W1, Wt1, 256, 256);
    k_wt<<<(256 * 64 + 255) / 256, 256, 0, stream>>>(W2, Wt2, 256, 64);

    int mtiles = (N + 127) / 128;

    // layer 1: A8 = fp8 grouped(Xb @ W1), then spmm -> B2 bf16 grouped
    dim3 g1(mtiles, 2);
    k_gemm<128, 2, 2, 0, 128, true><<<g1, 256, 0, stream>>>(Xb, Wt1, A8, N);
    k_spmm1<<<8192, 256, 0, stream>>>(A8, rp, es, inorm, onorm, b1, B2, N);

    // layer 2: Z = B2 @ W2 (plain [N][64] bf16), then spmm -> out fp32
    dim3 g2(mtiles, 1);
    k_gemm<64, 4, 1, 128, 0, false><<<g2, 256, 0, stream>>>(B2, Wt2, Z, N);
    k_spmm_out<<<8192, 256, 0, stream>>>(Z, rp, es, inorm, b2, out, N);
}